// Round 1
// baseline (754.385 us; speedup 1.0000x reference)
//
#include <hip/hip_runtime.h>
#include <math.h>

#define NN 25000
#define NE 400000
#define HD 64
#define EMBD 8
#define NG 16
#define NC 10

// ---------------------------------------------------------------------------
// K_pre: normalized edge directions, computed once (layer-invariant).
// d = c[src] - c[dst]; d /= max(||d||, 1e-12)
// ---------------------------------------------------------------------------
__global__ __launch_bounds__(256) void edge_dir_k(const float* __restrict__ c,
        const int* __restrict__ src, const int* __restrict__ dst,
        float* __restrict__ dnorm) {
    int e = blockIdx.x * 256 + threadIdx.x;
    if (e >= NE) return;
    int s = src[e], t = dst[e];
    float d[8];
#pragma unroll
    for (int i = 0; i < 8; i++) d[i] = c[s * 8 + i] - c[t * 8 + i];
    float nn = 0.f;
#pragma unroll
    for (int i = 0; i < 8; i++) nn += d[i] * d[i];
    float inv = 1.f / fmaxf(sqrtf(nn), 1e-12f);
#pragma unroll
    for (int i = 0; i < 8; i++) dnorm[(size_t)e * 8 + i] = d[i] * inv;
}

// ---------------------------------------------------------------------------
// K1: Z[n, i*64+k] = sum_j h[n,j] * W[i,j,k]
// block = 256 threads computes a 64(node) x 64(k) tile for one i (blockIdx.y).
// ---------------------------------------------------------------------------
__global__ __launch_bounds__(256) void node_gemm_k(const float* __restrict__ h,
        const float* __restrict__ W, float* __restrict__ Z) {
    __shared__ float hsT[64][68];   // [j][node_local], padded: 68*4B keeps 16B align
    __shared__ float Ws[64][64];    // [j][k] for fixed i
    int n0 = blockIdx.x * 64;
    int i  = blockIdx.y;
    int tx = threadIdx.x;

    // load W_i tile (coalesced)
    for (int t = tx; t < 4096; t += 256)
        Ws[t >> 6][t & 63] = W[i * 4096 + t];
    // load h tile transposed (global coalesced)
    for (int t = tx; t < 4096; t += 256) {
        int r = t >> 6, j = t & 63;
        int n = n0 + r;
        hsT[j][r] = (n < NN) ? h[(size_t)n * 64 + j] : 0.f;
    }
    __syncthreads();

    int col0 = (tx & 15) * 4;
    int row0 = (tx >> 4) * 4;
    float acc[4][4] = {{0.f}};
#pragma unroll 8
    for (int j = 0; j < 64; j++) {
        float4 a = *(const float4*)&hsT[j][row0];
        float4 b = *(const float4*)&Ws[j][col0];
        float a4[4] = {a.x, a.y, a.z, a.w};
        float b4[4] = {b.x, b.y, b.z, b.w};
#pragma unroll
        for (int r = 0; r < 4; r++)
#pragma unroll
            for (int cc = 0; cc < 4; cc++)
                acc[r][cc] = fmaf(a4[r], b4[cc], acc[r][cc]);
    }
#pragma unroll
    for (int r = 0; r < 4; r++) {
        int n = n0 + row0 + r;
        if (n < NN) {
            float4 v = make_float4(acc[r][0], acc[r][1], acc[r][2], acc[r][3]);
            *(float4*)(Z + (size_t)n * 512 + i * 64 + col0) = v;
        }
    }
}

// ---------------------------------------------------------------------------
// K2: per-edge msg[k] = sum_i dnorm[e,i] * Z[src, i*64+k]; atomicAdd to agg[dst].
// one wave (64 lanes = 64 channels) per edge, grid-stride over edges.
// ---------------------------------------------------------------------------
__global__ __launch_bounds__(256) void edge_msg_k(const float* __restrict__ dnorm,
        const int* __restrict__ src, const int* __restrict__ dst,
        const float* __restrict__ Z, float* agg) {
    int gid  = blockIdx.x * 256 + threadIdx.x;
    int wave = gid >> 6;
    int lane = threadIdx.x & 63;
    int nw   = (gridDim.x * 256) >> 6;
    for (int e = wave; e < NE; e += nw) {
        int s = src[e];
        int t = dst[e];
        const float* zp = Z + (size_t)s * 512 + lane;
        const float* dp = dnorm + (size_t)e * 8;
        float4 dA = *(const float4*)(dp);
        float4 dB = *(const float4*)(dp + 4);
        float m = 0.f;
        m = fmaf(dA.x, zp[0 * 64], m);
        m = fmaf(dA.y, zp[1 * 64], m);
        m = fmaf(dA.z, zp[2 * 64], m);
        m = fmaf(dA.w, zp[3 * 64], m);
        m = fmaf(dB.x, zp[4 * 64], m);
        m = fmaf(dB.y, zp[5 * 64], m);
        m = fmaf(dB.z, zp[6 * 64], m);
        m = fmaf(dB.w, zp[7 * 64], m);
        atomicAdd(agg + (size_t)t * 64 + lane, m);
    }
}

// ---------------------------------------------------------------------------
// K3: BN stats over relu(agg): per-channel sum & sumsq (64 channels).
// ---------------------------------------------------------------------------
__global__ __launch_bounds__(256) void bn_stats_k(const float* __restrict__ agg,
        float* sums, float* sumsq) {
    __shared__ float ls[256], ls2[256];
    int tx = threadIdx.x;
    int idx0 = blockIdx.x * 256 + tx;
    int stride = gridDim.x * 256;   // multiple of 64 -> channel fixed per thread
    float s = 0.f, s2 = 0.f;
    for (int idx = idx0; idx < NN * 64; idx += stride) {
        float x = fmaxf(agg[idx], 0.f);
        s += x;
        s2 += x * x;
    }
    ls[tx] = s; ls2[tx] = s2;
    __syncthreads();
    if (tx < 64) {
        s  = ls[tx] + ls[tx + 64] + ls[tx + 128] + ls[tx + 192];
        s2 = ls2[tx] + ls2[tx + 64] + ls2[tx + 128] + ls2[tx + 192];
        atomicAdd(&sums[tx], s);
        atomicAdd(&sumsq[tx], s2);
    }
}

// ---------------------------------------------------------------------------
// K4: BN apply + optional shortcut; writes h_new (may alias agg);
// accumulates graph pooling via LDS partials -> global atomics.
// ---------------------------------------------------------------------------
__global__ __launch_bounds__(256) void bn_apply_k(const float* agg,
        const float* __restrict__ h_old, const float* __restrict__ sums,
        const float* __restrict__ sumsq, const float* __restrict__ gamma,
        const float* __restrict__ beta, const int* __restrict__ gids,
        float* h_new, float* pooled, int shortcut) {
    __shared__ float pl[NG * 64];
    int tx = threadIdx.x;
    for (int t = tx; t < NG * 64; t += 256) pl[t] = 0.f;
    __syncthreads();

    int k = tx & 63;
    float mean = sums[k] * (1.f / NN);
    float var  = sumsq[k] * (1.f / NN) - mean * mean;
    float rstd = rsqrtf(var + 1e-5f);
    float g = gamma[k], b = beta[k];

    int idx0 = blockIdx.x * 256 + tx;
    int stride = gridDim.x * 256;
    for (int idx = idx0; idx < NN * 64; idx += stride) {
        int n = idx >> 6;
        float x = fmaxf(agg[idx], 0.f);
        float y = g * (x - mean) * rstd + b;
        if (shortcut) y += h_old[idx];
        h_new[idx] = y;
        atomicAdd(&pl[gids[n] * 64 + k], y);
    }
    __syncthreads();
    for (int t = tx; t < NG * 64; t += 256) {
        float v = pl[t];
        if (v != 0.f) atomicAdd(&pooled[t], v);
    }
}

// ---------------------------------------------------------------------------
// K5: classifier on pooled [16,64] -> logits += relu(BN(pooled@cW1+cb1))@cW2+cb2
// single block, 512 threads.
// ---------------------------------------------------------------------------
__global__ __launch_bounds__(512) void classifier_k(const float* __restrict__ pooled,
        const float* __restrict__ cW1, const float* __restrict__ cb1,
        const float* __restrict__ cg1, const float* __restrict__ cbt1,
        const float* __restrict__ cW2, const float* __restrict__ cb2,
        float* logits) {
    __shared__ float P[NG * 64];
    __shared__ float H1[NG * 32];
    __shared__ float cmu[32], crs[32];
    int tx = threadIdx.x;
    for (int t = tx; t < NG * 64; t += 512) P[t] = pooled[t];
    __syncthreads();

    int gidx = tx >> 5;       // 0..15
    int c    = tx & 31;       // 0..31
    float acc = cb1[c];
#pragma unroll 16
    for (int j = 0; j < 64; j++) acc = fmaf(P[gidx * 64 + j], cW1[j * 32 + c], acc);
    H1[gidx * 32 + c] = acc;
    __syncthreads();

    if (tx < 32) {
        float mu = 0.f;
#pragma unroll
        for (int g2 = 0; g2 < NG; g2++) mu += H1[g2 * 32 + tx];
        mu *= (1.f / NG);
        float v = 0.f;
#pragma unroll
        for (int g2 = 0; g2 < NG; g2++) {
            float d = H1[g2 * 32 + tx] - mu;
            v += d * d;
        }
        v *= (1.f / NG);
        cmu[tx] = mu;
        crs[tx] = rsqrtf(v + 1e-5f);
    }
    __syncthreads();

    float h1 = fmaxf(cg1[c] * (H1[gidx * 32 + c] - cmu[c]) * crs[c] + cbt1[c], 0.f);
    __syncthreads();
    H1[gidx * 32 + c] = h1;
    __syncthreads();

    if (tx < NG * NC) {
        int gg = tx / NC, cls = tx % NC;
        float a2 = cb2[cls];
#pragma unroll
        for (int j = 0; j < 32; j++) a2 = fmaf(H1[gg * 32 + j], cW2[j * NC + cls], a2);
        logits[tx] += a2;
    }
}

// ---------------------------------------------------------------------------
extern "C" void kernel_launch(void* const* d_in, const int* in_sizes, int n_in,
                              void* d_out, int out_size, void* d_ws, size_t ws_size,
                              hipStream_t stream) {
    const float* feature = (const float*)d_in[0];
    const float* cemb    = (const float*)d_in[1];
    const int*   src     = (const int*)d_in[2];
    const int*   dst     = (const int*)d_in[3];
    const int*   gids    = (const int*)d_in[4];
    const float* W[3]    = {(const float*)d_in[5], (const float*)d_in[6], (const float*)d_in[7]};
    const float* gam[3]  = {(const float*)d_in[8], (const float*)d_in[10], (const float*)d_in[12]};
    const float* bet[3]  = {(const float*)d_in[9], (const float*)d_in[11], (const float*)d_in[13]};
    const float* cW1  = (const float*)d_in[14];
    const float* cb1  = (const float*)d_in[15];
    const float* cg1  = (const float*)d_in[16];
    const float* cbt1 = (const float*)d_in[17];
    const float* cW2  = (const float*)d_in[18];
    const float* cb2  = (const float*)d_in[19];
    float* out = (float*)d_out;

    // workspace layout (floats)
    float* ws     = (float*)d_ws;
    float* dnorm  = ws;                       // 400000*8   = 3,200,000
    float* Z      = dnorm + (size_t)NE * 8;   // 25000*512  = 12,800,000
    float* bufX   = Z + (size_t)NN * 512;     // 25000*64   = 1,600,000
    float* bufY   = bufX + (size_t)NN * 64;   // 25000*64   = 1,600,000
    float* sums   = bufY + (size_t)NN * 64;   // 64
    float* sumsq  = sums + 64;                // 64
    float* pooled = sumsq + 64;               // 16*64 = 1024

    hipMemsetAsync(d_out, 0, (size_t)NG * NC * sizeof(float), stream);
    edge_dir_k<<<(NE + 255) / 256, 256, 0, stream>>>(cemb, src, dst, dnorm);

    const float* h_old = feature;
    float* bufs[2] = {bufX, bufY};
    for (int l = 0; l < 3; l++) {
        float* agg = bufs[l & 1];  // L0:X, L1:Y (reads X), L2:X (reads Y)
        hipMemsetAsync(agg, 0, (size_t)NN * 64 * sizeof(float), stream);
        hipMemsetAsync(sums, 0, (64 + 64 + NG * 64) * sizeof(float), stream);

        node_gemm_k<<<dim3((NN + 63) / 64, 8), 256, 0, stream>>>(h_old, W[l], Z);
        edge_msg_k<<<2048, 256, 0, stream>>>(dnorm, src, dst, Z, agg);
        bn_stats_k<<<256, 256, 0, stream>>>(agg, sums, sumsq);
        bn_apply_k<<<256, 256, 0, stream>>>(agg, h_old, sums, sumsq, gam[l], bet[l],
                                            gids, agg /*in-place*/, pooled, l > 0);
        classifier_k<<<1, 512, 0, stream>>>(pooled, cW1, cb1, cg1, cbt1, cW2, cb2, out);
        h_old = agg;
    }
}

// Round 2
// 729.634 us; speedup vs baseline: 1.0339x; 1.0339x over previous
//
#include <hip/hip_runtime.h>
#include <math.h>

#define NN 25000
#define NE 400000
#define HD 64
#define EMBD 8
#define NG 16
#define NC 10

// ---------------------------------------------------------------------------
// Sort phase (once per launch; edge structure is layer-invariant).
// Counting sort by src so the Z-gather in edge_msg has locality.
// ---------------------------------------------------------------------------
__global__ __launch_bounds__(256) void hist_k(const int* __restrict__ src, int* cnt) {
    int e = blockIdx.x * 256 + threadIdx.x;
    if (e < NE) atomicAdd(&cnt[src[e]], 1);
}

// single-block exclusive scan of cnt[NN] -> cursor[NN]
__global__ __launch_bounds__(1024) void scan_k(const int* __restrict__ cnt, int* cursor) {
    __shared__ int sh[1024];
    __shared__ int carry;
    int tx = threadIdx.x;
    if (tx == 0) carry = 0;
    __syncthreads();
    for (int c0 = 0; c0 < NN; c0 += 1024) {
        int i = c0 + tx;
        int v = (i < NN) ? cnt[i] : 0;
        sh[tx] = v;
        __syncthreads();
        for (int off = 1; off < 1024; off <<= 1) {
            int t = (tx >= off) ? sh[tx - off] : 0;
            __syncthreads();
            sh[tx] += t;
            __syncthreads();
        }
        int excl = sh[tx] - v;
        if (i < NN) cursor[i] = carry + excl;
        int total = sh[1023];
        __syncthreads();
        if (tx == 0) carry += total;
        __syncthreads();
    }
}

// scatter: place each edge at its sorted position; compute normalized
// direction dnorm at the sorted slot (fuses old edge_dir_k).
__global__ __launch_bounds__(256) void scatter_k(const int* __restrict__ src,
        const int* __restrict__ dst, const float* __restrict__ c,
        int* cursor, int* __restrict__ src_s, int* __restrict__ dst_s,
        float* __restrict__ dnorm_s) {
    int e = blockIdx.x * 256 + threadIdx.x;
    if (e >= NE) return;
    int s = src[e], t = dst[e];
    int pos = atomicAdd(&cursor[s], 1);
    src_s[pos] = s;
    dst_s[pos] = t;
    float d[8];
#pragma unroll
    for (int i = 0; i < 8; i++) d[i] = c[s * 8 + i] - c[t * 8 + i];
    float nn = 0.f;
#pragma unroll
    for (int i = 0; i < 8; i++) nn += d[i] * d[i];
    float inv = 1.f / fmaxf(sqrtf(nn), 1e-12f);
    float4 lo = make_float4(d[0] * inv, d[1] * inv, d[2] * inv, d[3] * inv);
    float4 hi = make_float4(d[4] * inv, d[5] * inv, d[6] * inv, d[7] * inv);
    *(float4*)(dnorm_s + (size_t)pos * 8)     = lo;
    *(float4*)(dnorm_s + (size_t)pos * 8 + 4) = hi;
}

// ---------------------------------------------------------------------------
// K1: Z[n, i*64+k] = sum_j h[n,j] * W[i,j,k]
// ---------------------------------------------------------------------------
__global__ __launch_bounds__(256) void node_gemm_k(const float* __restrict__ h,
        const float* __restrict__ W, float* __restrict__ Z) {
    __shared__ float hsT[64][68];
    __shared__ float Ws[64][64];
    int n0 = blockIdx.x * 64;
    int i  = blockIdx.y;
    int tx = threadIdx.x;

    for (int t = tx; t < 4096; t += 256)
        Ws[t >> 6][t & 63] = W[i * 4096 + t];
    for (int t = tx; t < 4096; t += 256) {
        int r = t >> 6, j = t & 63;
        int n = n0 + r;
        hsT[j][r] = (n < NN) ? h[(size_t)n * 64 + j] : 0.f;
    }
    __syncthreads();

    int col0 = (tx & 15) * 4;
    int row0 = (tx >> 4) * 4;
    float acc[4][4] = {{0.f}};
#pragma unroll 8
    for (int j = 0; j < 64; j++) {
        float4 a = *(const float4*)&hsT[j][row0];
        float4 b = *(const float4*)&Ws[j][col0];
        float a4[4] = {a.x, a.y, a.z, a.w};
        float b4[4] = {b.x, b.y, b.z, b.w};
#pragma unroll
        for (int r = 0; r < 4; r++)
#pragma unroll
            for (int cc = 0; cc < 4; cc++)
                acc[r][cc] = fmaf(a4[r], b4[cc], acc[r][cc]);
    }
#pragma unroll
    for (int r = 0; r < 4; r++) {
        int n = n0 + row0 + r;
        if (n < NN) {
            float4 v = make_float4(acc[r][0], acc[r][1], acc[r][2], acc[r][3]);
            *(float4*)(Z + (size_t)n * 512 + i * 64 + col0) = v;
        }
    }
}

// ---------------------------------------------------------------------------
// K2: src-sorted edge pass. Wave = 64 channels of one edge; contiguous
// per-wave chunk so same-src runs reuse the Z row held in registers.
// ---------------------------------------------------------------------------
#define NWAVES 4096
__global__ __launch_bounds__(256) void edge_msg_k(const float* __restrict__ dnorm,
        const int* __restrict__ src_s, const int* __restrict__ dst_s,
        const float* __restrict__ Z, float* agg) {
    int gid  = blockIdx.x * 256 + threadIdx.x;
    int wave = gid >> 6;
    int lane = threadIdx.x & 63;
    const int cpw = (NE + NWAVES - 1) / NWAVES;
    int e0 = wave * cpw;
    int e1 = min(e0 + cpw, NE);
    int sprev = -1;
    float z0=0,z1=0,z2=0,z3=0,z4=0,z5=0,z6=0,z7=0;
    for (int e = e0; e < e1; e++) {
        int s = src_s[e];
        int t = dst_s[e];
        if (s != sprev) {
            const float* zp = Z + (size_t)s * 512 + lane;
            z0 = zp[0*64]; z1 = zp[1*64]; z2 = zp[2*64]; z3 = zp[3*64];
            z4 = zp[4*64]; z5 = zp[5*64]; z6 = zp[6*64]; z7 = zp[7*64];
            sprev = s;
        }
        const float* dp = dnorm + (size_t)e * 8;
        float4 dA = *(const float4*)(dp);
        float4 dB = *(const float4*)(dp + 4);
        float m = 0.f;
        m = fmaf(dA.x, z0, m);
        m = fmaf(dA.y, z1, m);
        m = fmaf(dA.z, z2, m);
        m = fmaf(dA.w, z3, m);
        m = fmaf(dB.x, z4, m);
        m = fmaf(dB.y, z5, m);
        m = fmaf(dB.z, z6, m);
        m = fmaf(dB.w, z7, m);
        atomicAdd(agg + (size_t)t * 64 + lane, m);
    }
}

// ---------------------------------------------------------------------------
// K3: BN stats over relu(agg)
// ---------------------------------------------------------------------------
__global__ __launch_bounds__(256) void bn_stats_k(const float* __restrict__ agg,
        float* sums, float* sumsq) {
    __shared__ float ls[256], ls2[256];
    int tx = threadIdx.x;
    int idx0 = blockIdx.x * 256 + tx;
    int stride = gridDim.x * 256;
    float s = 0.f, s2 = 0.f;
    for (int idx = idx0; idx < NN * 64; idx += stride) {
        float x = fmaxf(agg[idx], 0.f);
        s += x;
        s2 += x * x;
    }
    ls[tx] = s; ls2[tx] = s2;
    __syncthreads();
    if (tx < 64) {
        s  = ls[tx] + ls[tx + 64] + ls[tx + 128] + ls[tx + 192];
        s2 = ls2[tx] + ls2[tx + 64] + ls2[tx + 128] + ls2[tx + 192];
        atomicAdd(&sums[tx], s);
        atomicAdd(&sumsq[tx], s2);
    }
}

// ---------------------------------------------------------------------------
// K4: BN apply + shortcut + graph pooling (LDS partials -> atomics)
// ---------------------------------------------------------------------------
__global__ __launch_bounds__(256) void bn_apply_k(const float* agg,
        const float* __restrict__ h_old, const float* __restrict__ sums,
        const float* __restrict__ sumsq, const float* __restrict__ gamma,
        const float* __restrict__ beta, const int* __restrict__ gids,
        float* h_new, float* pooled, int shortcut) {
    __shared__ float pl[NG * 64];
    int tx = threadIdx.x;
    for (int t = tx; t < NG * 64; t += 256) pl[t] = 0.f;
    __syncthreads();

    int k = tx & 63;
    float mean = sums[k] * (1.f / NN);
    float var  = sumsq[k] * (1.f / NN) - mean * mean;
    float rstd = rsqrtf(var + 1e-5f);
    float g = gamma[k], b = beta[k];

    int idx0 = blockIdx.x * 256 + tx;
    int stride = gridDim.x * 256;
    for (int idx = idx0; idx < NN * 64; idx += stride) {
        int n = idx >> 6;
        float x = fmaxf(agg[idx], 0.f);
        float y = g * (x - mean) * rstd + b;
        if (shortcut) y += h_old[idx];
        h_new[idx] = y;
        atomicAdd(&pl[gids[n] * 64 + k], y);
    }
    __syncthreads();
    for (int t = tx; t < NG * 64; t += 256) {
        float v = pl[t];
        if (v != 0.f) atomicAdd(&pooled[t], v);
    }
}

// ---------------------------------------------------------------------------
// K5: classifier (single block)
// ---------------------------------------------------------------------------
__global__ __launch_bounds__(512) void classifier_k(const float* __restrict__ pooled,
        const float* __restrict__ cW1, const float* __restrict__ cb1,
        const float* __restrict__ cg1, const float* __restrict__ cbt1,
        const float* __restrict__ cW2, const float* __restrict__ cb2,
        float* logits) {
    __shared__ float P[NG * 64];
    __shared__ float H1[NG * 32];
    __shared__ float cmu[32], crs[32];
    int tx = threadIdx.x;
    for (int t = tx; t < NG * 64; t += 512) P[t] = pooled[t];
    __syncthreads();

    int gidx = tx >> 5;
    int c    = tx & 31;
    float acc = cb1[c];
#pragma unroll 16
    for (int j = 0; j < 64; j++) acc = fmaf(P[gidx * 64 + j], cW1[j * 32 + c], acc);
    H1[gidx * 32 + c] = acc;
    __syncthreads();

    if (tx < 32) {
        float mu = 0.f;
#pragma unroll
        for (int g2 = 0; g2 < NG; g2++) mu += H1[g2 * 32 + tx];
        mu *= (1.f / NG);
        float v = 0.f;
#pragma unroll
        for (int g2 = 0; g2 < NG; g2++) {
            float d = H1[g2 * 32 + tx] - mu;
            v += d * d;
        }
        v *= (1.f / NG);
        cmu[tx] = mu;
        crs[tx] = rsqrtf(v + 1e-5f);
    }
    __syncthreads();

    float h1 = fmaxf(cg1[c] * (H1[gidx * 32 + c] - cmu[c]) * crs[c] + cbt1[c], 0.f);
    __syncthreads();
    H1[gidx * 32 + c] = h1;
    __syncthreads();

    if (tx < NG * NC) {
        int gg = tx / NC, cls = tx % NC;
        float a2 = cb2[cls];
#pragma unroll
        for (int j = 0; j < 32; j++) a2 = fmaf(H1[gg * 32 + j], cW2[j * NC + cls], a2);
        logits[tx] += a2;
    }
}

// ---------------------------------------------------------------------------
extern "C" void kernel_launch(void* const* d_in, const int* in_sizes, int n_in,
                              void* d_out, int out_size, void* d_ws, size_t ws_size,
                              hipStream_t stream) {
    const float* feature = (const float*)d_in[0];
    const float* cemb    = (const float*)d_in[1];
    const int*   src     = (const int*)d_in[2];
    const int*   dst     = (const int*)d_in[3];
    const int*   gids    = (const int*)d_in[4];
    const float* W[3]    = {(const float*)d_in[5], (const float*)d_in[6], (const float*)d_in[7]};
    const float* gam[3]  = {(const float*)d_in[8], (const float*)d_in[10], (const float*)d_in[12]};
    const float* bet[3]  = {(const float*)d_in[9], (const float*)d_in[11], (const float*)d_in[13]};
    const float* cW1  = (const float*)d_in[14];
    const float* cb1  = (const float*)d_in[15];
    const float* cg1  = (const float*)d_in[16];
    const float* cbt1 = (const float*)d_in[17];
    const float* cW2  = (const float*)d_in[18];
    const float* cb2  = (const float*)d_in[19];
    float* out = (float*)d_out;

    // workspace layout
    float* ws      = (float*)d_ws;
    float* dnorm_s = ws;                          // NE*8    = 3,200,000 f
    float* Z       = dnorm_s + (size_t)NE * 8;    // NN*512  = 12,800,000 f
    float* bufX    = Z + (size_t)NN * 512;        // NN*64
    float* bufY    = bufX + (size_t)NN * 64;      // NN*64
    float* sums    = bufY + (size_t)NN * 64;      // 64
    float* sumsq   = sums + 64;                   // 64
    float* pooled  = sumsq + 64;                  // 1024
    int*   cnt     = (int*)(pooled + 1024);       // NN
    int*   cursor  = cnt + NN;                    // NN
    int*   src_s   = cursor + NN;                 // NE
    int*   dst_s   = src_s + NE;                  // NE

    hipMemsetAsync(d_out, 0, (size_t)NG * NC * sizeof(float), stream);
    hipMemsetAsync(cnt, 0, NN * sizeof(int), stream);

    // build src-sorted edge list once (layer-invariant)
    hist_k<<<(NE + 255) / 256, 256, 0, stream>>>(src, cnt);
    scan_k<<<1, 1024, 0, stream>>>(cnt, cursor);
    scatter_k<<<(NE + 255) / 256, 256, 0, stream>>>(src, dst, cemb, cursor,
                                                    src_s, dst_s, dnorm_s);

    const float* h_old = feature;
    float* bufs[2] = {bufX, bufY};
    for (int l = 0; l < 3; l++) {
        float* agg = bufs[l & 1];
        hipMemsetAsync(agg, 0, (size_t)NN * 64 * sizeof(float), stream);
        hipMemsetAsync(sums, 0, (64 + 64 + NG * 64) * sizeof(float), stream);

        node_gemm_k<<<dim3((NN + 63) / 64, 8), 256, 0, stream>>>(h_old, W[l], Z);
        edge_msg_k<<<NWAVES / 4, 256, 0, stream>>>(dnorm_s, src_s, dst_s, Z, agg);
        bn_stats_k<<<256, 256, 0, stream>>>(agg, sums, sumsq);
        bn_apply_k<<<256, 256, 0, stream>>>(agg, h_old, sums, sumsq, gam[l], bet[l],
                                            gids, agg, pooled, l > 0);
        classifier_k<<<1, 512, 0, stream>>>(pooled, cW1, cb1, cg1, cbt1, cW2, cb2, out);
        h_old = agg;
    }
}